// Round 1
// baseline (90.959 us; speedup 1.0000x reference)
//
#include <hip/hip_runtime.h>
#include <math.h>

// Problem constants (fixed by reference setup_inputs)
#define NN 32768
#define LL 256      // K dimension (leaves)
#define CC 64       // output cols (classes)

typedef __attribute__((ext_vector_type(8))) _Float16 half8;  // MFMA A/B frag (4 VGPRs)
typedef __attribute__((ext_vector_type(4))) float f32x4;     // MFMA C/D frag

// ---------------------------------------------------------------------------
// Fully fused: out = log( fp16(mu) @ softmax(leaf_scores) )
// Single kernel, NO workspace — the former prep pass (softmax -> B-fragment
// swizzle) is recomputed per block directly into LDS. Rationale: the harness
// re-poisons d_ws (256 MiB fill, ~45 us, dominates the timed window) and the
// extra launch serializes; per-block softmax is ~1-2 us of VALU/shuffle work
// that hides completely under the 5.3 us/CU of HBM A-traffic.
//
// Layouts (verified in prior rounds):
//   B-frag region (s,t): lane (q,m) holds B[k=s*32+q*8+j][n=t*16+m], j=0..7
//   C/D: col = lane&15, row = quad*4 + reg
//
// 512 blocks x 256 threads (4 waves). Wave: 16 rows x 64 cols, full K=256.
// Accuracy: fp16 truncation of A and B ~2^-11 rel -> log abs err ~5e-4
// (threshold 2.16e-2, prior absmax 3.9e-3). __expf/__logf/__fdividef add
// only ~1e-7 rel. Dropping the eps clamp is exact: mu>=0 and any value
// < 2^-24 rounds to fp16 zero with or without fmax(v,1e-12).
// ---------------------------------------------------------------------------
__global__ __launch_bounds__(256) void fused_leaf_mix_kernel(
    const float* __restrict__ mu, const float* __restrict__ scores,
    float* __restrict__ out) {
    __shared__ float Bs[8192];   // 32 KB of fp16 B fragments in MFMA order

    const int tid  = threadIdx.x;
    const int wid  = tid >> 6;
    const int lane = tid & 63;
    const int quad = lane >> 4;  // doubles as class-tile t during staging
    const int m    = lane & 15;

    // ---- prefetch first scores group BEFORE the A loads: vmcnt retires
    //      in issue order, so softmax group 0 waits only on L2, not HBM ----
    // wave wid owns groups g = wid*8 + gi; group g: s = g>>2, q = g&3;
    // rows l = s*32 + q*8 + j (j=0..7); lane = class k.
    float vn[8];
    {
        const int g = wid * 8;
        const int s = g >> 2, q = g & 3;
        const float* srow = scores + (s * 32 + q * 8) * CC + lane;
        #pragma unroll
        for (int j = 0; j < 8; ++j) vn[j] = srow[j * CC];
    }

    // ---- A fragment loads (HBM): lane m holds row, k-window = s*32+quad*8 ----
    const size_t row = (size_t)blockIdx.x * 64 + wid * 16 + m;
    const float* arow = mu + row * LL + quad * 8;
    float4 a[16];
    #pragma unroll
    for (int s = 0; s < 8; ++s) {
        a[2 * s]     = *(const float4*)(arow + s * 32);
        a[2 * s + 1] = *(const float4*)(arow + s * 32 + 4);
    }

    // ---- fused softmax(scores rows) -> fp16, scattered into B-frag order.
    //      Per group: 8 independent 12-shuffle reduction chains (good ILP);
    //      write is one conflict-free ds_write_b128 per lane. ----
    #pragma unroll
    for (int gi = 0; gi < 8; ++gi) {
        const int g = wid * 8 + gi;
        const int s = g >> 2, q = g & 3;
        float v[8];
        #pragma unroll
        for (int j = 0; j < 8; ++j) v[j] = vn[j];
        if (gi < 7) {  // prefetch next group's rows (L2-hot)
            const int gn = g + 1;
            const int sn = gn >> 2, qn = gn & 3;
            const float* srow = scores + (sn * 32 + qn * 8) * CC + lane;
            #pragma unroll
            for (int j = 0; j < 8; ++j) vn[j] = srow[j * CC];
        }
        half8 h;
        #pragma unroll
        for (int j = 0; j < 8; ++j) {
            float mx = v[j];
            #pragma unroll
            for (int off = 32; off > 0; off >>= 1)
                mx = fmaxf(mx, __shfl_xor(mx, off));
            const float e = __expf(v[j] - mx);
            float sum = e;
            #pragma unroll
            for (int off = 32; off > 0; off >>= 1)
                sum += __shfl_xor(sum, off);
            h[j] = (_Float16)__fdividef(e, sum);
        }
        // region (s, t=quad-of-class=lane>>4), slot q*16 + (k&15), elems j=0..7
        ((half8*)Bs)[(s * 4 + quad) * 64 + q * 16 + m] = h;
    }
    __syncthreads();

    f32x4 acc[4] = {{0.f, 0.f, 0.f, 0.f}, {0.f, 0.f, 0.f, 0.f},
                    {0.f, 0.f, 0.f, 0.f}, {0.f, 0.f, 0.f, 0.f}};

    #pragma unroll
    for (int s = 0; s < 8; ++s) {
        half8 ah;
        ah[0] = (_Float16)a[2 * s].x;     ah[1] = (_Float16)a[2 * s].y;
        ah[2] = (_Float16)a[2 * s].z;     ah[3] = (_Float16)a[2 * s].w;
        ah[4] = (_Float16)a[2 * s + 1].x; ah[5] = (_Float16)a[2 * s + 1].y;
        ah[6] = (_Float16)a[2 * s + 1].z; ah[7] = (_Float16)a[2 * s + 1].w;
        #pragma unroll
        for (int tt = 0; tt < 4; ++tt) {
            const half8 b = ((const half8*)Bs)[(s * 4 + tt) * 64 + lane];
            acc[tt] = __builtin_amdgcn_mfma_f32_16x16x32_f16(ah, b, acc[tt], 0, 0, 0);
        }
    }

    // ---- epilogue: C/D layout col = lane&15, row = quad*4 + reg ----
    const size_t outRow0 = (size_t)blockIdx.x * 64 + wid * 16 + quad * 4;
    #pragma unroll
    for (int tt = 0; tt < 4; ++tt)
        #pragma unroll
        for (int r = 0; r < 4; ++r)
            out[(outRow0 + r) * CC + tt * 16 + m] = __logf(acc[tt][r]);
}

extern "C" void kernel_launch(void* const* d_in, const int* in_sizes, int n_in,
                              void* d_out, int out_size, void* d_ws, size_t ws_size,
                              hipStream_t stream) {
    const float* mu     = (const float*)d_in[0];   // (32768, 256) f32
    const float* scores = (const float*)d_in[1];   // (256, 64)    f32
    float* out = (float*)d_out;                    // (32768, 64)  f32
    (void)d_ws; (void)ws_size;                     // workspace intentionally unused

    fused_leaf_mix_kernel<<<NN / 64, 256, 0, stream>>>(mu, scores, out);
}

// Round 2
// 79.738 us; speedup vs baseline: 1.1407x; 1.1407x over previous
//
#include <hip/hip_runtime.h>
#include <math.h>

// Problem constants (fixed by reference setup_inputs)
#define NN 32768
#define LL 256      // K dimension (leaves)
#define CC 64       // output cols (classes)

typedef __attribute__((ext_vector_type(8))) _Float16 half8;  // MFMA A/B frag (4 VGPRs)
typedef __attribute__((ext_vector_type(4))) float f32x4;     // MFMA C/D frag + load vec

// ---------------------------------------------------------------------------
// Fully fused: out = log( fp16(mu) @ softmax(leaf_scores) )   — single kernel.
//
// R1 post-mortem: the shuffle-reduce softmax cost ~3072 ds_bpermute per block
// (768/wave), saturating the LDS pipe for ~50 us. This version has ZERO
// cross-lane ops: 256 threads <-> 256 leaf rows, each thread computes its
// row's softmax serially in registers (scores row is L2-hot, 64 KB total),
// then scatters 64 fp16 probs into B-fragment order in LDS.
//
// LDS layout (logical, verified in prior rounds):
//   byte addr = s*4096 + tt*1024 + q*256 + m*16 + j*2
//   region (s,tt): lane (quad,m) holds B[k=s*32+quad*8+j][n=tt*16+m], j=0..7
// XOR swizzle (both sides, involution on bits 4-5):
//   write:  ... + ((m*16) ^ (q<<4))      -- spreads q into bank bits
//   read :  rlane = (lane*16) ^ (quad<<4) -- lane permutation, conflict-free
// (check: row 9 [s0,q1,j1], class 17 [tt1,m1] -> byte 1282 on both sides)
//
// 512 blocks x 256 threads (4 waves), 64 mu-rows per block, full K=256.
// Load order: scores (L2 ~200cy) THEN mu (HBM ~900cy); in-order vmcnt
// retirement lets softmax start when scores land, mu still in flight.
// Accuracy: fp16 truncation ~2^-11 rel -> log abs err ~5e-4 (threshold
// 2.16e-2; measured absmax 3.9e-3 in R0/R1 with identical numerics).
// ---------------------------------------------------------------------------
__global__ __launch_bounds__(256) void fused_leaf_mix_kernel(
    const float* __restrict__ mu, const float* __restrict__ scores,
    float* __restrict__ out) {
    __shared__ float Bs[8192];   // 32 KB of fp16 B fragments, XOR-swizzled

    const int tid  = threadIdx.x;
    const int wid  = tid >> 6;
    const int lane = tid & 63;
    const int quad = lane >> 4;
    const int m    = lane & 15;

    // ---- scores row loads FIRST: thread tid owns leaf row tid ----
    f32x4 sv[16];
    {
        const f32x4* srow = (const f32x4*)(scores + tid * CC);
        #pragma unroll
        for (int c = 0; c < 16; ++c) sv[c] = srow[c];
    }

    // ---- mu fragment loads (HBM): lane m = row, k-window = s*32 + quad*8 ----
    const size_t row = (size_t)blockIdx.x * 64 + wid * 16 + m;
    const float* arow = mu + row * LL + quad * 8;
    f32x4 a[16];
    #pragma unroll
    for (int s = 0; s < 8; ++s) {
        a[2 * s]     = *(const f32x4*)(arow + s * 32);
        a[2 * s + 1] = *(const f32x4*)(arow + s * 32 + 4);
    }

    // ---- per-row softmax entirely in registers: no cross-lane ops ----
    float mx = fmaxf(fmaxf(sv[0][0], sv[0][1]), fmaxf(sv[0][2], sv[0][3]));
    #pragma unroll
    for (int c = 1; c < 16; ++c)
        mx = fmaxf(mx, fmaxf(fmaxf(sv[c][0], sv[c][1]),
                             fmaxf(sv[c][2], sv[c][3])));
    float sum = 0.f;
    #pragma unroll
    for (int c = 0; c < 16; ++c) {
        sv[c][0] = __expf(sv[c][0] - mx);
        sv[c][1] = __expf(sv[c][1] - mx);
        sv[c][2] = __expf(sv[c][2] - mx);
        sv[c][3] = __expf(sv[c][3] - mx);
        sum += (sv[c][0] + sv[c][1]) + (sv[c][2] + sv[c][3]);
    }
    const float rs = __fdividef(1.0f, sum);

    // ---- scatter 64 fp16 probs into swizzled B-frag LDS layout ----
    {
        char* bs = (char*)Bs;
        const int s = tid >> 5, q = (tid >> 3) & 3, j = tid & 7;
        const int base = s * 4096 + q * 256 + j * 2;
        const int qx = q << 4;
        #pragma unroll
        for (int k = 0; k < 64; ++k) {
            const _Float16 h = (_Float16)(sv[k >> 2][k & 3] * rs);
            *(_Float16*)(bs + base + (k >> 4) * 1024 + (((k & 15) * 16) ^ qx)) = h;
        }
    }
    __syncthreads();

    f32x4 acc[4] = {{0.f, 0.f, 0.f, 0.f}, {0.f, 0.f, 0.f, 0.f},
                    {0.f, 0.f, 0.f, 0.f}, {0.f, 0.f, 0.f, 0.f}};

    const char* bsr = (const char*)Bs;
    const int rlane = (lane * 16) ^ (quad << 4);  // swizzled, conflict-free
    #pragma unroll
    for (int s = 0; s < 8; ++s) {
        half8 ah;
        ah[0] = (_Float16)a[2 * s][0];     ah[1] = (_Float16)a[2 * s][1];
        ah[2] = (_Float16)a[2 * s][2];     ah[3] = (_Float16)a[2 * s][3];
        ah[4] = (_Float16)a[2 * s + 1][0]; ah[5] = (_Float16)a[2 * s + 1][1];
        ah[6] = (_Float16)a[2 * s + 1][2]; ah[7] = (_Float16)a[2 * s + 1][3];
        #pragma unroll
        for (int tt = 0; tt < 4; ++tt) {
            const half8 b = *(const half8*)(bsr + (s * 4 + tt) * 1024 + rlane);
            acc[tt] = __builtin_amdgcn_mfma_f32_16x16x32_f16(ah, b, acc[tt], 0, 0, 0);
        }
    }

    // ---- epilogue: C/D layout col = lane&15, row = quad*4 + reg ----
    const size_t outRow0 = (size_t)blockIdx.x * 64 + wid * 16 + quad * 4;
    #pragma unroll
    for (int tt = 0; tt < 4; ++tt)
        #pragma unroll
        for (int r = 0; r < 4; ++r)
            out[(outRow0 + r) * CC + tt * 16 + m] = __logf(acc[tt][r]);
}

extern "C" void kernel_launch(void* const* d_in, const int* in_sizes, int n_in,
                              void* d_out, int out_size, void* d_ws, size_t ws_size,
                              hipStream_t stream) {
    const float* mu     = (const float*)d_in[0];   // (32768, 256) f32
    const float* scores = (const float*)d_in[1];   // (256, 64)    f32
    float* out = (float*)d_out;                    // (32768, 64)  f32
    (void)d_ws; (void)ws_size;                     // workspace intentionally unused

    fused_leaf_mix_kernel<<<NN / 64, 256, 0, stream>>>(mu, scores, out);
}

// Round 3
// 78.715 us; speedup vs baseline: 1.1555x; 1.0130x over previous
//
#include <hip/hip_runtime.h>
#include <math.h>

// Problem constants (fixed by reference setup_inputs)
#define NN 32768
#define LL 256      // K dimension (leaves)
#define CC 64       // output cols (classes)

typedef __attribute__((ext_vector_type(8))) _Float16 half8;  // MFMA A/B frag (4 VGPRs)
typedef __attribute__((ext_vector_type(4))) _Float16 half4;  // 8B LDS store
typedef __attribute__((ext_vector_type(4))) float f32x4;     // MFMA C/D frag + load vec

// ---------------------------------------------------------------------------
// Two-kernel structure (R2 post-mortem: the 256 MiB ws poison-fill happens
// UNCONDITIONALLY every iteration, so using d_ws is free; in-kernel softmax
// x512 blocks bought nothing and its uncoalesced scores loads hurt).
//
// prep_kernel (verified R0): softmax(leaf_scores) rows -> fp16, scattered
// into MFMA B-fragment order in ws. 256 blocks x 64 threads, ~2 us.
//   B-frag region (s,t): lane (q,m) holds B[k=s*32+q*8+j][n=t*16+m], j=0..7
// ---------------------------------------------------------------------------
__global__ __launch_bounds__(64) void prep_kernel(
    const float* __restrict__ scores, _Float16* __restrict__ wsB) {
    const int l = blockIdx.x;    // leaf row
    const int k = threadIdx.x;   // class col
    float v = scores[(size_t)l * CC + k];
    float mx = v;
    #pragma unroll
    for (int off = 32; off > 0; off >>= 1) mx = fmaxf(mx, __shfl_xor(mx, off));
    float e = __expf(v - mx);
    float sum = e;
    #pragma unroll
    for (int off = 32; off > 0; off >>= 1) sum += __shfl_xor(sum, off);
    _Float16 h = (_Float16)__fdividef(e, sum);

    const int s = l >> 5;          // k-step
    const int w = l & 31;
    const int q = w >> 3;          // quad within frag
    const int j = w & 7;           // element within frag
    const int t = k >> 4;          // n-tile
    const int m = k & 15;          // n within tile
    wsB[((s * 4 + t) * 64 + q * 16 + m) * 8 + j] = h;
}

// ---------------------------------------------------------------------------
// Main kernel: out = log( fp16(mu) @ Q )  via fp16 MFMA.
//
// R0/R1/R2 all spent ~30-40 us in uncoalesced loads (A-frag loads: lanes
// 1024B apart, 16B granules -> TA-pipe serialization with only 2 blocks/CU
// to hide it). Fix: COALESCED mu loads (lane-consecutive float4, 1KB/inst),
// cvt to fp16, stage via XOR-swizzled LDS A-tile; read fragments as
// ds_read_b128.
//
// A-LDS layout: A16[row][col] fp16, 512B row stride; byte addr =
//   (row*512 + col*2) ^ ((row&7)<<4)   (same involution on write + read;
//   spot-check row13,k37 -> byte 6682 both sides). Read pattern hits the
//   b128 minimum (8 addrs/bank) like the canonical contiguous pattern.
// B path identical to verified R0: coalesced ws copy -> LDS -> contiguous
//   half8 reads (0 bank conflicts measured in R1).
//
// 512 blocks x 256 threads (4 waves), 64 rows/block, full K=256.
// LDS = 32KB A + 32KB B = 64KB -> 2 blocks/CU.
// Load order: B (8 float4, L2/HBM) then A (16 float4, HBM); in-order vmcnt
// lets B's LDS write start while A is still in flight.
// Accuracy: identical numerics to R0 (absmax 3.9e-3, threshold 2.16e-2).
// ---------------------------------------------------------------------------
__global__ __launch_bounds__(256) void leaf_mix_mfma_kernel(
    const float* __restrict__ mu, const float4* __restrict__ wsB,
    float* __restrict__ out) {
    __shared__ float Bs[8192];            // 32 KB fp16 B fragments (frag order)
    __shared__ _Float16 As[64 * 256];     // 32 KB fp16 A tile, XOR-swizzled

    const int tid  = threadIdx.x;
    const int wid  = tid >> 6;
    const int lane = tid & 63;
    const int quad = lane >> 4;
    const int m    = lane & 15;

    // ---- B loads first (ws, 32 KB): coalesced float4, 1KB/inst ----
    float4 breg[8];
    #pragma unroll
    for (int i = 0; i < 8; ++i) breg[i] = wsB[tid + 256 * i];

    // ---- A loads (mu block tile, 64 KB): fully coalesced float4 ----
    // float4 idx = i*256 + tid  ->  row = i*4 + wid, cols [lane*4, lane*4+4)
    f32x4 areg[16];
    const f32x4* mublk = (const f32x4*)(mu + (size_t)blockIdx.x * 64 * LL);
    #pragma unroll
    for (int i = 0; i < 16; ++i) areg[i] = mublk[i * 256 + tid];

    // ---- stage B to LDS (waits vmcnt for B group only; A still in flight) ----
    {
        float4* dst = (float4*)Bs;
        #pragma unroll
        for (int i = 0; i < 8; ++i) dst[tid + 256 * i] = breg[i];
    }

    // ---- cvt A to fp16 + swizzled LDS write: 8B/lane, conflict-free ----
    {
        char* as = (char*)As;
        #pragma unroll
        for (int i = 0; i < 16; ++i) {
            const int row = i * 4 + wid;
            half4 h;
            h[0] = (_Float16)areg[i][0]; h[1] = (_Float16)areg[i][1];
            h[2] = (_Float16)areg[i][2]; h[3] = (_Float16)areg[i][3];
            *(half4*)(as + ((row * 512 + lane * 8) ^ ((row & 7) << 4))) = h;
        }
    }
    __syncthreads();

    f32x4 acc[4] = {{0.f, 0.f, 0.f, 0.f}, {0.f, 0.f, 0.f, 0.f},
                    {0.f, 0.f, 0.f, 0.f}, {0.f, 0.f, 0.f, 0.f}};

    const char* asr = (const char*)As;
    const char* bsr = (const char*)Bs;
    const int arow   = wid * 16 + m;
    const int abase0 = arow * 512 + quad * 16;   // logical byte addr, s*64 added per step
    const int axm    = (m & 7) << 4;             // swizzle mask (row&7 == m&7 here)
    #pragma unroll
    for (int s = 0; s < 8; ++s) {
        const half8 ah = *(const half8*)(asr + ((abase0 + s * 64) ^ axm));
        #pragma unroll
        for (int tt = 0; tt < 4; ++tt) {
            const half8 b = *(const half8*)(bsr + (s * 4 + tt) * 1024 + lane * 16);
            acc[tt] = __builtin_amdgcn_mfma_f32_16x16x32_f16(ah, b, acc[tt], 0, 0, 0);
        }
    }

    // ---- epilogue: C/D layout col = lane&15, row = quad*4 + reg ----
    const size_t outRow0 = (size_t)blockIdx.x * 64 + wid * 16 + quad * 4;
    #pragma unroll
    for (int tt = 0; tt < 4; ++tt)
        #pragma unroll
        for (int r = 0; r < 4; ++r)
            out[(outRow0 + r) * CC + tt * 16 + m] = __logf(acc[tt][r]);
}

extern "C" void kernel_launch(void* const* d_in, const int* in_sizes, int n_in,
                              void* d_out, int out_size, void* d_ws, size_t ws_size,
                              hipStream_t stream) {
    const float* mu     = (const float*)d_in[0];   // (32768, 256) f32
    const float* scores = (const float*)d_in[1];   // (256, 64)    f32
    float* out = (float*)d_out;                    // (32768, 64)  f32

    prep_kernel<<<LL, CC, 0, stream>>>(scores, (_Float16*)d_ws);
    leaf_mix_mfma_kernel<<<NN / 64, 256, 0, stream>>>(mu, (const float4*)d_ws, out);
}

// Round 4
// 78.306 us; speedup vs baseline: 1.1616x; 1.0052x over previous
//
#include <hip/hip_runtime.h>
#include <math.h>

// Problem constants (fixed by reference setup_inputs)
#define NN 32768
#define LL 256      // K dimension (leaves)
#define CC 64       // output cols (classes)

typedef __attribute__((ext_vector_type(8))) _Float16 half8;  // MFMA A/B frag (4 VGPRs)
typedef __attribute__((ext_vector_type(4))) _Float16 half4;  // 8B LDS store
typedef __attribute__((ext_vector_type(4))) float f32x4;     // MFMA C/D frag + load vec

// global -> LDS direct copy, 16B per lane. LDS dest must be the WAVE-UNIFORM
// base (HW adds lane*16 itself); global src is per-lane.
#define GLOAD_LDS16(g, l)                                                   \
    __builtin_amdgcn_global_load_lds(                                       \
        (const __attribute__((address_space(1))) void*)(g),                 \
        (__attribute__((address_space(3))) void*)(l), 16, 0, 0)

// ---------------------------------------------------------------------------
// prep_kernel (verified R0/R3): softmax(leaf_scores) rows -> fp16, scattered
// into MFMA B-fragment order in ws. 256 blocks x 64 threads, ~2 us.
//   B-frag region (s,t): lane (q,m) holds B[k=s*32+q*8+j][n=t*16+m], j=0..7
// ---------------------------------------------------------------------------
__global__ __launch_bounds__(64) void prep_kernel(
    const float* __restrict__ scores, _Float16* __restrict__ wsB) {
    const int l = blockIdx.x;    // leaf row
    const int k = threadIdx.x;   // class col
    float v = scores[(size_t)l * CC + k];
    float mx = v;
    #pragma unroll
    for (int off = 32; off > 0; off >>= 1) mx = fmaxf(mx, __shfl_xor(mx, off));
    float e = __expf(v - mx);
    float sum = e;
    #pragma unroll
    for (int off = 32; off > 0; off >>= 1) sum += __shfl_xor(sum, off);
    _Float16 h = (_Float16)__fdividef(e, sum);

    const int s = l >> 5;          // k-step
    const int w = l & 31;
    const int q = w >> 3;          // quad within frag
    const int j = w & 7;           // element within frag
    const int t = k >> 4;          // n-tile
    const int m = k & 15;          // n within tile
    wsB[((s * 4 + t) * 64 + q * 16 + m) * 8 + j] = h;
}

// ---------------------------------------------------------------------------
// Main kernel: out = log( fp16(mu) @ Q )  via fp16 MFMA.
//
// R3 post-mortem: coalescing changed nothing (78.7 == baseline). R1's
// VGPR_Count=52 vs a declared 64-VGPR prefetch array shows the allocator's
// default occupancy target SINKS the A-loads into their uses — ~2-4 loads in
// flight instead of 24 — a serial latency chain that explains the
// structure-invariant ~35 us across R0/R2/R3.
//
// Fixes, both targeting in-flight bytes:
//   * __launch_bounds__(256, 2): LDS (64 KB) already caps at 2 blocks/CU =
//     2 waves/EU, so the wider VGPR cap is free and keeps all 16 A-float4s
//     resident/in-flight.
//   * B staged via global_load_lds (fragment order is LINEAR: uniform base +
//     lane*16 = exact HW pattern): no VGPR round-trip, and B's 8 loads stay
//     in flight under the whole A phase (vmcnt-drained at the barrier).
//
// A path / MFMA loop / epilogue byte-identical to R3 (harness-verified,
// absmax 3.9e-3, threshold 2.16e-2):
//   A-LDS: byte addr = (row*512 + col*2) ^ ((row&7)<<4), same involution on
//   write (half4 per lane) and fragment read (ds_read_b128).
// ---------------------------------------------------------------------------
__global__ __launch_bounds__(256, 2) void leaf_mix_mfma_kernel(
    const float* __restrict__ mu, const float4* __restrict__ wsB,
    float* __restrict__ out) {
    __shared__ float Bs[8192];            // 32 KB fp16 B fragments (frag order)
    __shared__ _Float16 As[64 * 256];     // 32 KB fp16 A tile, XOR-swizzled

    const int tid  = threadIdx.x;
    const int wid  = tid >> 6;
    const int lane = tid & 63;
    const int quad = lane >> 4;
    const int m    = lane & 15;

    // ---- B: ws -> LDS direct, zero VGPRs, stays in flight all phase ----
    {
        const char* gsrc = (const char*)wsB;
        char* lbase = (char*)Bs;
        #pragma unroll
        for (int i = 0; i < 8; ++i) {
            const int blk16 = i * 256 + wid * 64;            // 16B units
            GLOAD_LDS16(gsrc + ((size_t)blk16 + lane) * 16,  // per-lane src
                        lbase + (size_t)blk16 * 16);         // uniform dest
        }
    }

    // ---- A: 16 coalesced float4 loads, ALL issued before any use ----
    // float4 idx = i*256 + tid  ->  row = i*4 + wid, cols [lane*4, lane*4+4)
    f32x4 areg[16];
    const f32x4* mublk = (const f32x4*)(mu + (size_t)blockIdx.x * 64 * LL);
    #pragma unroll
    for (int i = 0; i < 16; ++i) areg[i] = mublk[i * 256 + tid];

    // ---- cvt A to fp16 + swizzled LDS write: 8B/lane, conflict-free ----
    {
        char* as = (char*)As;
        #pragma unroll
        for (int i = 0; i < 16; ++i) {
            const int row = i * 4 + wid;
            half4 h;
            h[0] = (_Float16)areg[i][0]; h[1] = (_Float16)areg[i][1];
            h[2] = (_Float16)areg[i][2]; h[3] = (_Float16)areg[i][3];
            *(half4*)(as + ((row * 512 + lane * 8) ^ ((row & 7) << 4))) = h;
        }
    }
    __syncthreads();   // compiler emits vmcnt(0): B's global_load_lds drained

    f32x4 acc[4] = {{0.f, 0.f, 0.f, 0.f}, {0.f, 0.f, 0.f, 0.f},
                    {0.f, 0.f, 0.f, 0.f}, {0.f, 0.f, 0.f, 0.f}};

    const char* asr = (const char*)As;
    const char* bsr = (const char*)Bs;
    const int arow   = wid * 16 + m;
    const int abase0 = arow * 512 + quad * 16;   // logical byte addr, +s*64/step
    const int axm    = (m & 7) << 4;             // swizzle mask (row&7 == m&7)
    #pragma unroll
    for (int s = 0; s < 8; ++s) {
        const half8 ah = *(const half8*)(asr + ((abase0 + s * 64) ^ axm));
        #pragma unroll
        for (int tt = 0; tt < 4; ++tt) {
            const half8 b = *(const half8*)(bsr + (s * 4 + tt) * 1024 + lane * 16);
            acc[tt] = __builtin_amdgcn_mfma_f32_16x16x32_f16(ah, b, acc[tt], 0, 0, 0);
        }
    }

    // ---- epilogue: C/D layout col = lane&15, row = quad*4 + reg ----
    const size_t outRow0 = (size_t)blockIdx.x * 64 + wid * 16 + quad * 4;
    #pragma unroll
    for (int tt = 0; tt < 4; ++tt)
        #pragma unroll
        for (int r = 0; r < 4; ++r)
            out[(outRow0 + r) * CC + tt * 16 + m] = __logf(acc[tt][r]);
}

extern "C" void kernel_launch(void* const* d_in, const int* in_sizes, int n_in,
                              void* d_out, int out_size, void* d_ws, size_t ws_size,
                              hipStream_t stream) {
    const float* mu     = (const float*)d_in[0];   // (32768, 256) f32
    const float* scores = (const float*)d_in[1];   // (256, 64)    f32
    float* out = (float*)d_out;                    // (32768, 64)  f32

    prep_kernel<<<LL, CC, 0, stream>>>(scores, (_Float16*)d_ws);
    leaf_mix_mfma_kernel<<<NN / 64, 256, 0, stream>>>(mu, (const float4*)d_ws, out);
}